// Round 1
// baseline (16.405 us; speedup 1.0000x reference)
//
#include <hip/hip_runtime.h>

// 4-qubit statevector sim, fully in registers.
// Flat index i = b0*8 + b1*4 + b2*2 + b3 (qubit 0 = MSB, matching the
// reference's reshape(b,2,2,2,2) with axis q+1 = qubit q).
//
// Pre-CNOT state is a product state: amp = prod_q t_q[b_q].
// CNOT(0->1);CNOT(1->2);CNOT(2->3) compose to:
//   state[b0,b1,b2,b3] = pre[b0, b1^b0, b2^b1, b3^b2]
// so we build the post-CNOT state directly.

__global__ __launch_bounds__(256) void quantum4_kernel(
    const float* __restrict__ x, const float* __restrict__ w,
    float* __restrict__ out, int n)
{
    int b = blockIdx.x * blockDim.x + threadIdx.x;
    if (b >= n) return;

    float4 xv = reinterpret_cast<const float4*>(x)[b];

    float c0, s0, c1, s1, c2, s2, c3, s3;
    __sincosf(xv.x * 0.5f, &s0, &c0);
    __sincosf(xv.y * 0.5f, &s1, &c1);
    __sincosf(xv.z * 0.5f, &s2, &c2);
    __sincosf(xv.w * 0.5f, &s3, &c3);

    float wc[4], ws[4];
#pragma unroll
    for (int q = 0; q < 4; ++q) {
        __sincosf(w[q] * 0.5f, &ws[q], &wc[q]);
    }

    float t0[2] = {c0, s0}, t1[2] = {c1, s1}, t2[2] = {c2, s2}, t3[2] = {c3, s3};

    // Post-CNOT state, built directly via the composed permutation.
    float a[16];
#pragma unroll
    for (int i = 0; i < 16; ++i) {
        int b0 = (i >> 3) & 1, b1 = (i >> 2) & 1, b2 = (i >> 1) & 1, b3 = i & 1;
        a[i] = t0[b0] * t1[b1 ^ b0] * t2[b2 ^ b1] * t3[b3 ^ b2];
    }

    // RY(w_q) on qubit q: butterfly over pairs differing in bit (3-q).
#pragma unroll
    for (int q = 0; q < 4; ++q) {
        int str = 8 >> q;
#pragma unroll
        for (int i = 0; i < 16; ++i) {
            if ((i & str) == 0) {
                float A = a[i], Bv = a[i | str];
                a[i]       = wc[q] * A - ws[q] * Bv;
                a[i | str] = ws[q] * A + wc[q] * Bv;
            }
        }
    }

    // Z expectations: out[q] = sum amp^2 * (bit_q ? -1 : +1)
    float o0 = 0.f, o1 = 0.f, o2 = 0.f, o3 = 0.f;
#pragma unroll
    for (int i = 0; i < 16; ++i) {
        float p = a[i] * a[i];
        o0 += (i & 8) ? -p : p;
        o1 += (i & 4) ? -p : p;
        o2 += (i & 2) ? -p : p;
        o3 += (i & 1) ? -p : p;
    }

    reinterpret_cast<float4*>(out)[b] = make_float4(o0, o1, o2, o3);
}

extern "C" void kernel_launch(void* const* d_in, const int* in_sizes, int n_in,
                              void* d_out, int out_size, void* d_ws, size_t ws_size,
                              hipStream_t stream) {
    const float* x = (const float*)d_in[0];   // [B,4] f32
    const float* w = (const float*)d_in[1];   // [4]   f32
    float* out = (float*)d_out;               // [B,4] f32

    int n = in_sizes[0] / 4;                  // B
    int block = 256;
    int grid = (n + block - 1) / block;
    quantum4_kernel<<<grid, block, 0, stream>>>(x, w, out, n);
}

// Round 2
// 11.339 us; speedup vs baseline: 1.4468x; 1.4468x over previous
//
#include <hip/hip_runtime.h>

// Closed-form 4-qubit circuit evaluation.
//
// out[q] = <psi| RY_q(w_q)^T Z_q RY_q(w_q) |psi>  with |psi> the CNOT-chained
// product state of RY(x_q)|0>. Heisenberg-picture conjugation gives
//   RY(t)^T Z RY(t) = cos t * Z - sin t * X
// and pushing Z_q / X_q through C01,C12,C23 onto the product state:
//   <Z_q>  = c0*...*cq            (cq = cos x_q)
//   <X_0>  = s0*s1, <X_1> = s1*s2, <X_2> = s2*s3, <X_3> = s3   (sq = sin x_q)
// so
//   out0 = cw0*c0          - sw0*s0*s1
//   out1 = cw1*c0c1        - sw1*s1*s2
//   out2 = cw2*c0c1c2      - sw2*s2*s3
//   out3 = cw3*c0c1c2c3    - sw3*s3

__global__ __launch_bounds__(256) void quantum4_closed(
    const float* __restrict__ x, const float* __restrict__ w,
    float* __restrict__ out, int n)
{
    int b = blockIdx.x * blockDim.x + threadIdx.x;
    if (b >= n) return;

    float4 xv = reinterpret_cast<const float4*>(x)[b];

    float cw0, sw0, cw1, sw1, cw2, sw2, cw3, sw3;
    __sincosf(w[0], &sw0, &cw0);
    __sincosf(w[1], &sw1, &cw1);
    __sincosf(w[2], &sw2, &cw2);
    __sincosf(w[3], &sw3, &cw3);

    float s0, c0, s1, c1, s2, c2, s3, c3;
    __sincosf(xv.x, &s0, &c0);
    __sincosf(xv.y, &s1, &c1);
    __sincosf(xv.z, &s2, &c2);
    __sincosf(xv.w, &s3, &c3);

    float z1 = c0;
    float z2 = z1 * c1;
    float z3 = z2 * c2;
    float z4 = z3 * c3;

    float4 o;
    o.x = cw0 * z1 - sw0 * (s0 * s1);
    o.y = cw1 * z2 - sw1 * (s1 * s2);
    o.z = cw2 * z3 - sw2 * (s2 * s3);
    o.w = cw3 * z4 - sw3 * s3;

    reinterpret_cast<float4*>(out)[b] = o;
}

extern "C" void kernel_launch(void* const* d_in, const int* in_sizes, int n_in,
                              void* d_out, int out_size, void* d_ws, size_t ws_size,
                              hipStream_t stream) {
    const float* x = (const float*)d_in[0];   // [B,4] f32
    const float* w = (const float*)d_in[1];   // [4]   f32
    float* out = (float*)d_out;               // [B,4] f32

    int n = in_sizes[0] / 4;                  // B
    int block = 256;
    int grid = (n + block - 1) / block;
    quantum4_closed<<<grid, block, 0, stream>>>(x, w, out, n);
}